// Round 9
// baseline (4022.030 us; speedup 1.0000x reference)
//
#include <hip/hip_runtime.h>
#include <hip/hip_bf16.h>

// Problem constants (fixed shapes per reference setup_inputs; n_step = 200).
#define MM 64
#define NN 4096
#define KK 4096
#define NSTEP 200
#define NSLICE 8     // K-slice blocks per strip (k = bx>>5)
#define NSTRIP 32    // 128-column strips (s = bx&31; bx%8==s%8 -> strip-local XCD)
#define NPART 8      // P slices (one per gemm block after kh 4-way LDS reduction)

#define WLO_SCALE 16384.0f          // 2^14: lifts W residual into fp8 e4m3 range
#define WLO_INV   6.103515625e-05f  // 2^-14

typedef _Float16 f16x8 __attribute__((ext_vector_type(8)));
typedef float    f32x4 __attribute__((ext_vector_type(4)));

static __device__ __forceinline__ unsigned short f2h(float f) {
    _Float16 h = (_Float16)f;
    return __builtin_bit_cast(unsigned short, h);
}
static __device__ __forceinline__ float h2f(unsigned short u) {
    return (float)__builtin_bit_cast(_Float16, u);
}

// Fragment layouts (16x16x32 MFMA family, m89 mapping:
//   frag[lane=q*16+l16][j] = Mat[row16=l16][k=q*8+j], j=0..7 k-ascending):
// A (g):  elem(m,kg) = ((kc*4 + (m>>4))*64 + q*16 + (m&15))*8 + j
// B (W):  elem(n,kg) = (((s*8 + ns)*128 + kc)*64 + q*16 + (n&15))*8 + j
// Arrays indexed by ELEMENT: ushort for fp16, uchar for fp8 (same formula).
// Partials P[part 8][s 32][row 64][col 128] fp32 (8 MB); part = k.
// Precision: pre = (gh+gl)@Wh + g8@Wl8*2^-14; Wh=fp16(W), Wl8=fp8((W-Wh)*2^14)
// -> deltaW ~ |W|*2^-16, per-step error ~4e-6 (round-1 calib: final ~+0.001).

// ---------------------------------------------------------------------------
// Prologue 1: s = 0.5*(W[n][k]+W[k][n]), diag zero; split into fp16 hi frag
// array + scaled fp8 lo frag array. 64x64 tiles, LDS transpose.
// ---------------------------------------------------------------------------
__global__ __launch_bounds__(256) void symm_kernel(const float* __restrict__ W,
                                                   unsigned short* __restrict__ Wfh,
                                                   unsigned char*  __restrict__ Wfl8) {
    __shared__ float T[64][65];
    const int tid = threadIdx.x;
    const int r0 = blockIdx.y * 64, c0 = blockIdx.x * 64;
#pragma unroll
    for (int i = 0; i < 4; ++i) {
        int lin = tid + i * 256;
        int cc  = lin >> 4;
        int r4  = (lin & 15) * 4;
        float4 v = *(const float4*)&W[(size_t)(c0 + cc) * NN + r0 + r4];
        T[cc][r4 + 0] = v.x; T[cc][r4 + 1] = v.y;
        T[cc][r4 + 2] = v.z; T[cc][r4 + 3] = v.w;
    }
    __syncthreads();
#pragma unroll
    for (int i = 0; i < 4; ++i) {
        int lin = tid + i * 256;
        int rr  = lin >> 4;
        int c4  = (lin & 15) * 4;
        float4 v = *(const float4*)&W[(size_t)(r0 + rr) * NN + c0 + c4];
        float d[4] = {v.x, v.y, v.z, v.w};
        ushort4 ohi;
        unsigned short* ph = (unsigned short*)&ohi;
        float rs[4];
#pragma unroll
        for (int j = 0; j < 4; ++j) {
            float sv = 0.5f * (d[j] + T[c4 + j][rr]);
            if (r0 + rr == c0 + c4 + j) sv = 0.0f;
            unsigned short hi = f2h(sv);
            ph[j] = hi;
            rs[j] = (sv - h2f(hi)) * WLO_SCALE;
        }
        int pk = __builtin_amdgcn_cvt_pk_fp8_f32(rs[0], rs[1], 0, false);
        pk     = __builtin_amdgcn_cvt_pk_fp8_f32(rs[2], rs[3], pk, true);

        const int n  = r0 + rr;            // W row == output column
        const int kg = c0 + c4;            // 4-aligned -> j0 in {0,4}
        const int s_ = n >> 7, ns = (n >> 4) & 7, ln = n & 15;
        const int kc = kg >> 5, q = (kg & 31) >> 3, j0 = kg & 7;
        size_t off = ((((size_t)(s_ * 8 + ns) * 128 + kc) * 64 + q * 16 + ln)) * 8 + j0;
        *(ushort4*)&Wfh[off] = ohi;                 // 8B-aligned
        *(unsigned int*)&Wfl8[off] = (unsigned int)pk;  // 4B-aligned
    }
}

// ---------------------------------------------------------------------------
// Prologue 2: x0 = (1/beta)*log(g/(1-g)); g -> fp16 hi/lo + fp8 A-frags
// ---------------------------------------------------------------------------
__global__ __launch_bounds__(256) void init_kernel(const float* __restrict__ g_in,
                                                   const float* __restrict__ beta,
                                                   float* __restrict__ x,
                                                   unsigned short* __restrict__ gfh,
                                                   unsigned short* __restrict__ gfl,
                                                   unsigned char*  __restrict__ gf8) {
    int idx = blockIdx.x * 256 + threadIdx.x;
    int r = idx >> 12, c = idx & (NN - 1);
    float g = g_in[idx];
    x[idx] = logf(g / (1.0f - g)) / beta[c];
    unsigned short hi = f2h(g);
    size_t off = (((size_t)(c >> 5) * 4 + (r >> 4)) * 64 + ((c & 31) >> 3) * 16 + (r & 15)) * 8 + (c & 7);
    gfh[off] = hi;
    gfl[off] = f2h(g - h2f(hi));
    int p8 = __builtin_amdgcn_cvt_pk_fp8_f32(g, g, 0, false);
    gf8[off] = (unsigned char)(p8 & 0xff);
}

// ---------------------------------------------------------------------------
// Prologue 3: max_x = 50 / max(beta)
// ---------------------------------------------------------------------------
__global__ __launch_bounds__(256) void maxx_kernel(const float* __restrict__ beta,
                                                   float* __restrict__ out) {
    __shared__ float red[256];
    float m = -1e30f;
    for (int i = threadIdx.x; i < NN; i += 256) m = fmaxf(m, beta[i]);
    red[threadIdx.x] = m;
    __syncthreads();
    for (int s = 128; s > 0; s >>= 1) {
        if (threadIdx.x < s) red[threadIdx.x] = fmaxf(red[threadIdx.x], red[threadIdx.x + s]);
        __syncthreads();
    }
    if (threadIdx.x == 0) out[0] = 50.0f / red[0];
}

// ---------------------------------------------------------------------------
// GEMM partials: grid 256 = (k = bx>>5) x (s = bx&31), 1024 thr (16 waves).
// bx%8 == s%8 -> all 8 k-blocks of a strip land on one XCD (P stays L2-local).
// Wave w: mh=w&1, nh=(w>>1)&1, kh=w>>2. Per iter: 10x16B + 6x8B coalesced
// frag loads, 16 f16 MFMAs + 8 fp8 MFMAs (separate scaled accumulator).
// kh>0 waves dump combined acc to LDS; kh==0 waves reduce 4-way, write P[k][s].
// ---------------------------------------------------------------------------
__global__ __launch_bounds__(1024, 1) void gemm_kernel(
    const unsigned short* __restrict__ gfh,
    const unsigned short* __restrict__ gfl,
    const unsigned char*  __restrict__ gf8,
    const unsigned short* __restrict__ Wfh,
    const unsigned char*  __restrict__ Wfl8,
    float* __restrict__ P)
{
    __shared__ float sacc[12][32][64];   // 96 KB

    const int tid  = threadIdx.x;
    const int w    = tid >> 6;
    const int lane = tid & 63;
    const int q    = lane >> 4;
    const int l16  = lane & 15;

    const int k = blockIdx.x >> 5;
    const int s = blockIdx.x & 31;

    const int mh = w & 1;
    const int nh = (w >> 1) & 1;
    const int kh = w >> 2;               // 0..3

    f32x4 acc[2][4]  = {};
    f32x4 acc8[2][4] = {};

#pragma unroll
    for (int it = 0; it < 4; ++it) {
        const int kc = k * 16 + kh * 4 + it;
        const size_t aB = ((size_t)kc * 4) * 512 + lane * 8;
        const size_t bB = (((size_t)(s * 8) * 128 + kc) * 64 + lane) * 8;
        f16x8 ah[2], al[2], bh[4];
        unsigned long long a8[2], b8[4];
#pragma unroll
        for (int mi = 0; mi < 2; ++mi) {
            const size_t a = aB + (size_t)(mh * 2 + mi) * 512;
            ah[mi] = *(const f16x8*)&gfh[a];
            al[mi] = *(const f16x8*)&gfl[a];
            a8[mi] = *(const unsigned long long*)&gf8[a];
        }
#pragma unroll
        for (int ni = 0; ni < 4; ++ni) {
            const size_t b = bB + (size_t)(nh * 4 + ni) * 128 * 512;
            bh[ni] = *(const f16x8*)&Wfh[b];
            b8[ni] = *(const unsigned long long*)&Wfl8[b];
        }
#pragma unroll
        for (int mi = 0; mi < 2; ++mi)
#pragma unroll
            for (int ni = 0; ni < 4; ++ni) {
                acc[mi][ni]  = __builtin_amdgcn_mfma_f32_16x16x32_f16(ah[mi], bh[ni], acc[mi][ni], 0, 0, 0);
                acc[mi][ni]  = __builtin_amdgcn_mfma_f32_16x16x32_f16(al[mi], bh[ni], acc[mi][ni], 0, 0, 0);
                acc8[mi][ni] = __builtin_amdgcn_mfma_f32_16x16x32_fp8_fp8(
                                   (long long)a8[mi], (long long)b8[ni], acc8[mi][ni], 0, 0, 0);
            }
    }

    // combine scaled fp8 term, then kh-reduce through LDS
    float t[2][4][4];
#pragma unroll
    for (int mi = 0; mi < 2; ++mi)
#pragma unroll
        for (int ni = 0; ni < 4; ++ni)
#pragma unroll
            for (int rg = 0; rg < 4; ++rg)
                t[mi][ni][rg] = acc[mi][ni][rg] + acc8[mi][ni][rg] * WLO_INV;

    if (kh > 0) {
#pragma unroll
        for (int mi = 0; mi < 2; ++mi)
#pragma unroll
            for (int ni = 0; ni < 4; ++ni)
#pragma unroll
                for (int rg = 0; rg < 4; ++rg)
                    sacc[w - 4][(mi * 4 + ni) * 4 + rg][lane] = t[mi][ni][rg];
    }
    __syncthreads();
    if (kh == 0) {
        float* Pb = &P[((size_t)(k * NSTRIP + s) * 64) * 128];
#pragma unroll
        for (int mi = 0; mi < 2; ++mi)
#pragma unroll
            for (int ni = 0; ni < 4; ++ni)
#pragma unroll
                for (int rg = 0; rg < 4; ++rg) {
                    const int idx = (mi * 4 + ni) * 4 + rg;
                    const int row = mh * 32 + mi * 16 + q * 4 + rg;
                    const int col = nh * 64 + ni * 16 + l16;
                    float v = t[mi][ni][rg]
                            + sacc[w][idx][lane]
                            + sacc[w + 4][idx][lane]
                            + sacc[w + 8][idx][lane];
                    Pb[(size_t)row * 128 + col] = v;
                }
    }
}

// ---------------------------------------------------------------------------
// Epilogue: 256 blocks x 128 thr. Block bx: strip s = bx&31 (bx%8==s%8 ->
// reads P from its own XCD's L2), rows m in [8*(bx>>5), 8*(bx>>5)+8).
// Thread: one row, 8 cols. Sums 8 partials, b/alpha/clip/sigmoid, updates x,
// writes next-step g frags (fp16 hi/lo + fp8); fp32 g on the last step.
// ---------------------------------------------------------------------------
__global__ __launch_bounds__(128) void epi_kernel(
    const float* __restrict__ P,
    float* __restrict__ x,
    unsigned short* __restrict__ gfh_out,
    unsigned short* __restrict__ gfl_out,
    unsigned char*  __restrict__ gf8_out,
    const float* __restrict__ bvec,
    const float* __restrict__ beta,
    const float* __restrict__ tau,
    const float* __restrict__ dt_ptr,
    const float* __restrict__ maxx_ptr,
    float* __restrict__ gout_f32)             // non-null on last step only
{
    const int tid = threadIdx.x;
    const int s   = blockIdx.x & 31;
    const int m   = (blockIdx.x >> 5) * 8 + (tid >> 4);
    const int n0  = s * 128 + (tid & 15) * 8;   // 8-aligned

    float sum[8] = {};
#pragma unroll
    for (int kp = 0; kp < NPART; ++kp) {
        const float* p = &P[((size_t)(kp * NSTRIP + s) * 64 + m) * 128 + (n0 & 127)];
        float4 p0 = *(const float4*)&p[0];
        float4 p1 = *(const float4*)&p[4];
        sum[0] += p0.x; sum[1] += p0.y; sum[2] += p0.z; sum[3] += p0.w;
        sum[4] += p1.x; sum[5] += p1.y; sum[6] += p1.z; sum[7] += p1.w;
    }

    const float dt = *dt_ptr;
    const float mx = *maxx_ptr;
    float4 b0 = *(const float4*)&bvec[n0], b1 = *(const float4*)&bvec[n0 + 4];
    float4 e0 = *(const float4*)&beta[n0], e1 = *(const float4*)&beta[n0 + 4];
    float4 t0 = *(const float4*)&tau[n0],  t1 = *(const float4*)&tau[n0 + 4];
    float bb[8] = {b0.x, b0.y, b0.z, b0.w, b1.x, b1.y, b1.z, b1.w};
    float be[8] = {e0.x, e0.y, e0.z, e0.w, e1.x, e1.y, e1.z, e1.w};
    float tv[8] = {t0.x, t0.y, t0.z, t0.w, t1.x, t1.y, t1.z, t1.w};

    float* xp = &x[(size_t)m * NN + n0];
    float4 x0 = *(const float4*)&xp[0], x1 = *(const float4*)&xp[4];
    float xo[8] = {x0.x, x0.y, x0.z, x0.w, x1.x, x1.y, x1.z, x1.w};

    float gg[8];
    unsigned short vh[8], vl[8];
#pragma unroll
    for (int j = 0; j < 8; ++j) {
        const float al = dt / tv[j];
        float xn = al * (sum[j] + bb[j]) + (1.0f - al) * xo[j];
        xn = fminf(fmaxf(xn, -mx), mx);
        float g = 1.0f / (1.0f + __expf(-be[j] * xn));
        xo[j] = xn;
        gg[j] = g;
        unsigned short hi = f2h(g);
        vh[j] = hi;
        vl[j] = f2h(g - h2f(hi));
    }
    *(float4*)&xp[0] = {xo[0], xo[1], xo[2], xo[3]};
    *(float4*)&xp[4] = {xo[4], xo[5], xo[6], xo[7]};

    // A-fragment offset for (m, kg = n0..n0+7)
    size_t off = (((size_t)(n0 >> 5) * 4 + (m >> 4)) * 64 + ((n0 & 31) >> 3) * 16 + (m & 15)) * 8;
    *(ushort4*)&gfh_out[off]     = {vh[0], vh[1], vh[2], vh[3]};
    *(ushort4*)&gfh_out[off + 4] = {vh[4], vh[5], vh[6], vh[7]};
    *(ushort4*)&gfl_out[off]     = {vl[0], vl[1], vl[2], vl[3]};
    *(ushort4*)&gfl_out[off + 4] = {vl[4], vl[5], vl[6], vl[7]};

    int p0i = __builtin_amdgcn_cvt_pk_fp8_f32(gg[0], gg[1], 0, false);
    p0i     = __builtin_amdgcn_cvt_pk_fp8_f32(gg[2], gg[3], p0i, true);
    int p1i = __builtin_amdgcn_cvt_pk_fp8_f32(gg[4], gg[5], 0, false);
    p1i     = __builtin_amdgcn_cvt_pk_fp8_f32(gg[6], gg[7], p1i, true);
    *(unsigned int*)&gf8_out[off]     = (unsigned int)p0i;
    *(unsigned int*)&gf8_out[off + 4] = (unsigned int)p1i;

    if (gout_f32) {
        *(float4*)&gout_f32[(size_t)m * NN + n0]     = {gg[0], gg[1], gg[2], gg[3]};
        *(float4*)&gout_f32[(size_t)m * NN + n0 + 4] = {gg[4], gg[5], gg[6], gg[7]};
    }
}

// ---------------------------------------------------------------------------
extern "C" void kernel_launch(void* const* d_in, const int* in_sizes, int n_in,
                              void* d_out, int out_size, void* d_ws, size_t ws_size,
                              hipStream_t stream) {
    const float* state_g = (const float*)d_in[0];
    const float* W       = (const float*)d_in[1];
    const float* b       = (const float*)d_in[2];
    const float* beta    = (const float*)d_in[3];
    const float* tau     = (const float*)d_in[4];
    const float* dt      = (const float*)d_in[5];
    float* out = (float*)d_out;

    char* ws = (char*)d_ws;
    const size_t WH = (size_t)KK * NN * 2;    // 32 MB fp16 W-hi frags
    const size_t WL = (size_t)KK * NN;        // 16 MB fp8 W-lo frags
    const size_t XB = (size_t)MM * NN * 4;    // 1 MB
    const size_t GH = (size_t)MM * NN * 2;    // 512 KB fp16 g frags
    const size_t G8 = (size_t)MM * NN;        // 256 KB fp8 g frags
    const size_t PB = (size_t)NPART * NSTRIP * 64 * 128 * 4;   // 8 MB

    unsigned short* Wfh  = (unsigned short*)ws;
    unsigned char*  Wfl8 = (unsigned char*)(ws + WH);
    float*          x    = (float*)(ws + WH + WL);
    char* gbase = ws + WH + WL + XB;
    unsigned short* g0h = (unsigned short*)(gbase);
    unsigned short* g0l = (unsigned short*)(gbase + GH);
    unsigned char*  g08 = (unsigned char*)(gbase + 2 * GH);
    unsigned short* g1h = (unsigned short*)(gbase + 2 * GH + G8);
    unsigned short* g1l = (unsigned short*)(gbase + 3 * GH + G8);
    unsigned char*  g18 = (unsigned char*)(gbase + 4 * GH + G8);
    float*          P   = (float*)(gbase + 4 * GH + 2 * G8);
    float*          mxp = (float*)(gbase + 4 * GH + 2 * G8 + PB);

    symm_kernel<<<dim3(64, 64), 256, 0, stream>>>(W, Wfh, Wfl8);
    init_kernel<<<(MM * NN) / 256, 256, 0, stream>>>(state_g, beta, x, g0h, g0l, g08);
    maxx_kernel<<<1, 256, 0, stream>>>(beta, mxp);

    unsigned short *gih = g0h, *gil = g0l, *goh = g1h, *gol = g1l;
    unsigned char  *gi8 = g08, *go8 = g18;
    for (int st = 0; st < NSTEP; ++st) {
        float* of = (st == NSTEP - 1) ? out : nullptr;
        gemm_kernel<<<NSTRIP * NSLICE, 1024, 0, stream>>>(gih, gil, gi8, Wfh, Wfl8, P);
        epi_kernel<<<256, 128, 0, stream>>>(P, x, goh, gol, go8, b, beta, tau, dt, mxp, of);
        unsigned short* tp;
        tp = gih; gih = goh; goh = tp;
        tp = gil; gil = gol; gol = tp;
        unsigned char* t8 = gi8; gi8 = go8; go8 = t8;
    }
}